// Round 12
// baseline (185.503 us; speedup 1.0000x reference)
//
#include <hip/hip_runtime.h>
#include <hip/hip_bf16.h>
#include <hip/hip_cooperative_groups.h>

namespace cg = cooperative_groups;

#define NB 4096   // batch rows
#define NI 256    // input dim
#define NO 256    // output dim
#define NE 8      // experts
#define GRID 256  // one block per CU; cooperative co-residency guaranteed

// Device-global scratch. Invariant: g_meta is ZERO at entry to every call
// (zero-init at load; re-zeroed by block 0 at the end of every call).
__device__ int g_meta[16];          // [0..7] per-expert count, [8] overflow count
__device__ int g_rowlist[NE * NB];  // per-expert row indices (single-hot rows)
__device__ int g_ovf[NB];           // packed (mask<<16)|row for tie rows

// Single fused kernel: router -> grid.sync -> grouped GEMM -> grid.sync ->
// tie fix-up + meta reset (block 0). LDS reused across phases via one buffer.
__global__ __launch_bounds__(256, 4) void fused_kernel(
    const float* __restrict__ x, const float* __restrict__ W,
    const float* __restrict__ Wp, const float* __restrict__ bp,
    float* __restrict__ out)
{
    __shared__ __align__(16) float smem[2176];  // router: 2048 | gemm: 1088+1024
    __shared__ int rlds[64];

    const int t   = threadIdx.x;
    const int bid = blockIdx.x;

    // ---------------- Phase 1: router (16 rows per block) ----------------
    {
        float* wplds = smem;  // 2048 floats = Wp[8][256]
        #pragma unroll
        for (int i = 0; i < NE * NI; i += 256 * 4)
            *(float4*)&wplds[i + t * 4] = *(const float4*)&Wp[i + t * 4];
        __syncthreads();

        const int lane = t & 63;
        const int wv   = t >> 6;
        #pragma unroll
        for (int i = 0; i < 4; ++i) {
            const int b = bid * 16 + wv * 4 + i;
            const float4 xv = *(const float4*)&x[b * NI + lane * 4];
            float p[NE];
            #pragma unroll
            for (int e = 0; e < NE; ++e) {
                const float4 wq = *(const float4*)&wplds[e * NI + lane * 4];
                p[e] = xv.x * wq.x + xv.y * wq.y + xv.z * wq.z + xv.w * wq.w;
            }
            #pragma unroll
            for (int off = 32; off >= 1; off >>= 1) {
                #pragma unroll
                for (int e = 0; e < NE; ++e) p[e] += __shfl_xor(p[e], off);
            }
            float g[NE], gmax = -1e30f;
            #pragma unroll
            for (int e = 0; e < NE; ++e) {
                g[e] = 1.0f / (1.0f + expf(-(p[e] + bp[e])));
                gmax = fmaxf(gmax, g[e]);
            }
            int mask = 0;
            #pragma unroll
            for (int e = 0; e < NE; ++e) mask |= (g[e] == gmax) ? (1 << e) : 0;

            if (lane == 0) {
                if (__popc(mask) == 1) {
                    const int e = __ffs(mask) - 1;
                    const int pos = atomicAdd(&g_meta[e], 1);
                    g_rowlist[e * NB + pos] = b;
                } else {                    // tie: rare slow path
                    const int pos = atomicAdd(&g_meta[8], 1);
                    g_ovf[pos] = (mask << 16) | b;
                }
            }
        }
    }

    cg::this_grid().sync();

    // ---------------- Phase 2: grouped GEMM over binned rows ----------------
    {
        int cnts[NE];
        int tt = 0;
        #pragma unroll
        for (int e = 0; e < NE; ++e) { cnts[e] = g_meta[e]; tt += (cnts[e] + 63) >> 6; }
        const int TT4 = tt * 4;            // tiles x 4 n-chunks  (<= 284)

        float* xs  = smem;                 // [16][68] padded
        float* wst = smem + 1088;          // [16][64]

        for (int w = bid; w < TT4; w += GRID) {
            const int T  = w >> 2;
            const int n0 = (w & 3) * 64;
            int e = 0, base = 0, cnt = 0;
            for (; e < NE; ++e) {
                cnt = cnts[e];
                const int te = (cnt + 63) >> 6;
                if (T < base + te) break;
                base += te;
            }
            const int r0 = (T - base) * 64;

            if (t < 64) {
                const int idx = r0 + t;
                const int bb = g_rowlist[e * NB + min(idx, cnt - 1)];  // cnt>=1 here
                rlds[t] = (idx < cnt) ? bb : (bb | 0x40000000);        // bit30 = tail
            }
            __syncthreads();

            const int xm = t >> 2, xc = t & 3;
            const int wk = t >> 4, wc = t & 15;
            const float* xptr = x + (rlds[xm] & 0x3FFFFFFF) * NI + xc * 4;
            const float* wptr = W + e * NI * NO + wk * NO + n0 + wc * 4;
            float4 xr = *(const float4*)xptr;
            float4 wr = *(const float4*)wptr;

            const int tm = t >> 4, tn = t & 15;
            float acc[4][4] = {{0.f}};

            #pragma unroll 1
            for (int step = 0; step < 16; ++step) {
                __syncthreads();
                xs[(xc * 4 + 0) * 68 + xm] = xr.x;
                xs[(xc * 4 + 1) * 68 + xm] = xr.y;
                xs[(xc * 4 + 2) * 68 + xm] = xr.z;
                xs[(xc * 4 + 3) * 68 + xm] = xr.w;
                *(float4*)&wst[wk * 64 + wc * 4] = wr;
                __syncthreads();
                if (step < 15) {
                    xr = *(const float4*)(xptr + (step + 1) * 16);
                    wr = *(const float4*)(wptr + (step + 1) * 16 * NO);
                }
                #pragma unroll
                for (int k = 0; k < 16; ++k) {
                    const float4 a  = *(const float4*)&xs[k * 68 + tm * 4];
                    const float4 bv = *(const float4*)&wst[k * 64 + tn * 4];
                    acc[0][0] += a.x * bv.x; acc[0][1] += a.x * bv.y; acc[0][2] += a.x * bv.z; acc[0][3] += a.x * bv.w;
                    acc[1][0] += a.y * bv.x; acc[1][1] += a.y * bv.y; acc[1][2] += a.y * bv.z; acc[1][3] += a.y * bv.w;
                    acc[2][0] += a.z * bv.x; acc[2][1] += a.z * bv.y; acc[2][2] += a.z * bv.z; acc[2][3] += a.z * bv.w;
                    acc[3][0] += a.w * bv.x; acc[3][1] += a.w * bv.y; acc[3][2] += a.w * bv.z; acc[3][3] += a.w * bv.w;
                }
            }

            #pragma unroll
            for (int r = 0; r < 4; ++r) {
                const int info = rlds[tm * 4 + r];
                if (!(info & 0x40000000)) {
                    float4 v;
                    v.x = acc[r][0]; v.y = acc[r][1]; v.z = acc[r][2]; v.w = acc[r][3];
                    *(float4*)&out[(info & 0x3FFFFFFF) * NO + n0 + tn * 4] = v;
                }
            }
            __syncthreads();   // protect rlds/smem before next work item
        }
    }

    cg::this_grid().sync();

    // ------------- Phase 3: tie rows + meta reset (block 0 only) -------------
    if (bid == 0) {
        float* xl = smem;                  // 256 floats
        const int n = g_meta[8];
        for (int idx = 0; idx < n; ++idx) {
            const int packed = g_ovf[idx];
            const int b = packed & 0xFFFF;
            const int mask = packed >> 16;
            __syncthreads();
            xl[t] = x[b * NI + t];
            __syncthreads();
            float acc = 0.0f;
            for (int e = 0; e < NE; ++e) {
                if (mask & (1 << e)) {
                    const float* wp = W + e * NI * NO + t;
                    for (int i = 0; i < NI; ++i) acc += xl[i] * wp[i * NO];
                }
            }
            out[b * NO + t] = acc;
        }
        __syncthreads();                   // all reads of g_meta done
        if (t < 16) g_meta[t] = 0;         // restore invariant for next call
    }
}

extern "C" void kernel_launch(void* const* d_in, const int* in_sizes, int n_in,
                              void* d_out, int out_size, void* d_ws, size_t ws_size,
                              hipStream_t stream)
{
    const float* x  = (const float*)d_in[0];
    const float* W  = (const float*)d_in[1];
    const float* Wp = (const float*)d_in[2];
    const float* bp = (const float*)d_in[3];
    float*      out = (float*)d_out;

    void* args[] = { (void*)&x, (void*)&W, (void*)&Wp, (void*)&bp, (void*)&out };
    hipLaunchCooperativeKernel((void*)fused_kernel, dim3(GRID), dim3(256),
                               args, 0, stream);
}

// Round 15
// 181.519 us; speedup vs baseline: 1.0219x; 1.0219x over previous
//
#include <hip/hip_runtime.h>
#include <hip/hip_bf16.h>
#include <hip/hip_cooperative_groups.h>

namespace cg = cooperative_groups;

#define NB 4096   // batch rows
#define NI 256    // input dim
#define NO 256    // output dim
#define NE 8      // experts
#define GRID 256  // one block per CU; cooperative co-residency guaranteed

// Device-global scratch. Invariant: g_meta is ZERO at entry to every call
// (zero-init at load; re-zeroed by block 0 at the end of every call).
__device__ int g_meta[16];          // [0..7] per-expert count, [8] overflow count
__device__ int g_rowlist[NE * NB];  // per-expert row indices (single-hot rows)
__device__ int g_ovf[NB];           // packed (mask<<16)|row for tie rows

// Single fused kernel: router -> grid.sync -> grouped GEMM -> grid.sync ->
// tie fix-up + meta reset (block 0). LDS reused across phases via one buffer.
// NOTE: no min-occupancy arg in launch_bounds — round 12 showed (256,4)
// capped VGPRs at 52 and spilled acc[4][4] to scratch (105us, VALUBusy 6%).
__global__ __launch_bounds__(256) void fused_kernel(
    const float* __restrict__ x, const float* __restrict__ W,
    const float* __restrict__ Wp, const float* __restrict__ bp,
    float* __restrict__ out)
{
    __shared__ __align__(16) float smem[2176];  // router: 2048 | gemm: 1088+1024
    __shared__ int rlds[64];

    const int t   = threadIdx.x;
    const int bid = blockIdx.x;

    // ---------------- Phase 1: router (16 rows per block) ----------------
    {
        float* wplds = smem;  // 2048 floats = Wp[8][256]
        #pragma unroll
        for (int i = 0; i < NE * NI; i += 256 * 4)
            *(float4*)&wplds[i + t * 4] = *(const float4*)&Wp[i + t * 4];
        __syncthreads();

        const int lane = t & 63;
        const int wv   = t >> 6;
        #pragma unroll
        for (int i = 0; i < 4; ++i) {
            const int b = bid * 16 + wv * 4 + i;
            const float4 xv = *(const float4*)&x[b * NI + lane * 4];
            float p[NE];
            #pragma unroll
            for (int e = 0; e < NE; ++e) {
                const float4 wq = *(const float4*)&wplds[e * NI + lane * 4];
                p[e] = xv.x * wq.x + xv.y * wq.y + xv.z * wq.z + xv.w * wq.w;
            }
            #pragma unroll
            for (int off = 32; off >= 1; off >>= 1) {
                #pragma unroll
                for (int e = 0; e < NE; ++e) p[e] += __shfl_xor(p[e], off);
            }
            float g[NE], gmax = -1e30f;
            #pragma unroll
            for (int e = 0; e < NE; ++e) {
                g[e] = 1.0f / (1.0f + expf(-(p[e] + bp[e])));
                gmax = fmaxf(gmax, g[e]);
            }
            int mask = 0;
            #pragma unroll
            for (int e = 0; e < NE; ++e) mask |= (g[e] == gmax) ? (1 << e) : 0;

            if (lane == 0) {
                if (__popc(mask) == 1) {
                    const int e = __ffs(mask) - 1;
                    const int pos = atomicAdd(&g_meta[e], 1);
                    g_rowlist[e * NB + pos] = b;
                } else {                    // tie: rare slow path
                    const int pos = atomicAdd(&g_meta[8], 1);
                    g_ovf[pos] = (mask << 16) | b;
                }
            }
        }
    }

    cg::this_grid().sync();

    // ---------------- Phase 2: grouped GEMM over binned rows ----------------
    {
        int cnts[NE];
        int tt = 0;
        #pragma unroll
        for (int e = 0; e < NE; ++e) { cnts[e] = g_meta[e]; tt += (cnts[e] + 63) >> 6; }
        const int TT4 = tt * 4;            // tiles x 4 n-chunks  (<= 284)

        float* xs  = smem;                 // [16][68] padded
        float* wst = smem + 1088;          // [16][64]

        for (int w = bid; w < TT4; w += GRID) {
            const int T  = w >> 2;
            const int n0 = (w & 3) * 64;
            int e = 0, base = 0, cnt = 0;
            for (; e < NE; ++e) {
                cnt = cnts[e];
                const int te = (cnt + 63) >> 6;
                if (T < base + te) break;
                base += te;
            }
            const int r0 = (T - base) * 64;

            if (t < 64) {
                const int idx = r0 + t;
                const int bb = g_rowlist[e * NB + min(idx, cnt - 1)];  // cnt>=1 here
                rlds[t] = (idx < cnt) ? bb : (bb | 0x40000000);        // bit30 = tail
            }
            __syncthreads();

            const int xm = t >> 2, xc = t & 3;
            const int wk = t >> 4, wc = t & 15;
            const float* xptr = x + (rlds[xm] & 0x3FFFFFFF) * NI + xc * 4;
            const float* wptr = W + e * NI * NO + wk * NO + n0 + wc * 4;
            float4 xr = *(const float4*)xptr;
            float4 wr = *(const float4*)wptr;

            const int tm = t >> 4, tn = t & 15;
            float acc[4][4] = {{0.f}};

            #pragma unroll 1
            for (int step = 0; step < 16; ++step) {
                __syncthreads();
                xs[(xc * 4 + 0) * 68 + xm] = xr.x;
                xs[(xc * 4 + 1) * 68 + xm] = xr.y;
                xs[(xc * 4 + 2) * 68 + xm] = xr.z;
                xs[(xc * 4 + 3) * 68 + xm] = xr.w;
                *(float4*)&wst[wk * 64 + wc * 4] = wr;
                __syncthreads();
                if (step < 15) {
                    xr = *(const float4*)(xptr + (step + 1) * 16);
                    wr = *(const float4*)(wptr + (step + 1) * 16 * NO);
                }
                #pragma unroll
                for (int k = 0; k < 16; ++k) {
                    const float4 a  = *(const float4*)&xs[k * 68 + tm * 4];
                    const float4 bv = *(const float4*)&wst[k * 64 + tn * 4];
                    acc[0][0] += a.x * bv.x; acc[0][1] += a.x * bv.y; acc[0][2] += a.x * bv.z; acc[0][3] += a.x * bv.w;
                    acc[1][0] += a.y * bv.x; acc[1][1] += a.y * bv.y; acc[1][2] += a.y * bv.z; acc[1][3] += a.y * bv.w;
                    acc[2][0] += a.z * bv.x; acc[2][1] += a.z * bv.y; acc[2][2] += a.z * bv.z; acc[2][3] += a.z * bv.w;
                    acc[3][0] += a.w * bv.x; acc[3][1] += a.w * bv.y; acc[3][2] += a.w * bv.z; acc[3][3] += a.w * bv.w;
                }
            }

            #pragma unroll
            for (int r = 0; r < 4; ++r) {
                const int info = rlds[tm * 4 + r];
                if (!(info & 0x40000000)) {
                    float4 v;
                    v.x = acc[r][0]; v.y = acc[r][1]; v.z = acc[r][2]; v.w = acc[r][3];
                    *(float4*)&out[(info & 0x3FFFFFFF) * NO + n0 + tn * 4] = v;
                }
            }
            __syncthreads();   // protect rlds/smem before next work item
        }
    }

    cg::this_grid().sync();

    // ------------- Phase 3: tie rows + meta reset (block 0 only) -------------
    if (bid == 0) {
        float* xl = smem;                  // 256 floats
        const int n = g_meta[8];
        for (int idx = 0; idx < n; ++idx) {
            const int packed = g_ovf[idx];
            const int b = packed & 0xFFFF;
            const int mask = packed >> 16;
            __syncthreads();
            xl[t] = x[b * NI + t];
            __syncthreads();
            float acc = 0.0f;
            for (int e = 0; e < NE; ++e) {
                if (mask & (1 << e)) {
                    const float* wp = W + e * NI * NO + t;
                    for (int i = 0; i < NI; ++i) acc += xl[i] * wp[i * NO];
                }
            }
            out[b * NO + t] = acc;
        }
        __syncthreads();                   // all reads of g_meta done
        if (t < 16) g_meta[t] = 0;         // restore invariant for next call
    }
}

extern "C" void kernel_launch(void* const* d_in, const int* in_sizes, int n_in,
                              void* d_out, int out_size, void* d_ws, size_t ws_size,
                              hipStream_t stream)
{
    const float* x  = (const float*)d_in[0];
    const float* W  = (const float*)d_in[1];
    const float* Wp = (const float*)d_in[2];
    const float* bp = (const float*)d_in[3];
    float*      out = (float*)d_out;

    void* args[] = { (void*)&x, (void*)&W, (void*)&Wp, (void*)&bp, (void*)&out };
    hipLaunchCooperativeKernel((void*)fused_kernel, dim3(GRID), dim3(256),
                               args, 0, stream);
}

// Round 16
// 130.698 us; speedup vs baseline: 1.4193x; 1.3888x over previous
//
#include <hip/hip_runtime.h>
#include <hip/hip_bf16.h>

#define NB 4096   // batch rows
#define NI 256    // input dim
#define NO 256    // output dim
#define NE 8      // experts
#define NBLK 288  // gemm grid = 72 x 4

// Device-global scratch. Invariants at entry to every call:
//   g_meta == 0, g_done == 0  (zero-init at load; last gemm block resets both)
__device__ int g_meta[16];          // [0..7] per-expert count, [8] overflow count
__device__ int g_rowlist[NE * NB];  // per-expert row indices (single-hot rows)
__device__ int g_ovf[NB];           // packed (mask<<16)|row for tie rows
__device__ int g_done = 0;          // gemm blocks completed

// ---------------------------------------------------------------------------
// Router: g = sigmoid(x @ Wp^T + bp); bin rows by argmax expert (ties -> ovf).
// One wave per row; lane l owns x[b][4l..4l+3].  (Proven: rounds 10-11.)
// ---------------------------------------------------------------------------
__global__ __launch_bounds__(256) void router_kernel(
    const float* __restrict__ x, const float* __restrict__ Wp,
    const float* __restrict__ bp)
{
    __shared__ float wplds[NE * NI];
    const int t = threadIdx.x;
    #pragma unroll
    for (int i = 0; i < NE * NI; i += 256 * 4)
        *(float4*)&wplds[i + t * 4] = *(const float4*)&Wp[i + t * 4];
    __syncthreads();

    const int lane = t & 63;
    const int b = blockIdx.x * 4 + (t >> 6);
    const float4 xv = *(const float4*)&x[b * NI + lane * 4];

    float p[NE];
    #pragma unroll
    for (int e = 0; e < NE; ++e) {
        const float4 wv = *(const float4*)&wplds[e * NI + lane * 4];
        p[e] = xv.x * wv.x + xv.y * wv.y + xv.z * wv.z + xv.w * wv.w;
    }
    #pragma unroll
    for (int off = 32; off >= 1; off >>= 1) {
        #pragma unroll
        for (int e = 0; e < NE; ++e) p[e] += __shfl_xor(p[e], off);
    }
    float g[NE], gmax = -1e30f;
    #pragma unroll
    for (int e = 0; e < NE; ++e) {
        g[e] = 1.0f / (1.0f + expf(-(p[e] + bp[e])));
        gmax = fmaxf(gmax, g[e]);
    }
    int mask = 0;
    #pragma unroll
    for (int e = 0; e < NE; ++e) mask |= (g[e] == gmax) ? (1 << e) : 0;

    if (lane == 0) {
        if (__popc(mask) == 1) {
            const int e = __ffs(mask) - 1;
            const int pos = atomicAdd(&g_meta[e], 1);
            g_rowlist[e * NB + pos] = b;
        } else {                       // tie: rare slow path
            const int pos = atomicAdd(&g_meta[8], 1);
            g_ovf[pos] = (mask << 16) | b;
        }
    }
}

// ---------------------------------------------------------------------------
// Grouped GEMM over binned rows (round-11 body, proven fast standalone) +
// last-block finalize: tie rows, then reset g_meta/g_done for the next call.
// Ordering: every block reads g_meta BEFORE atomicAdd(g_done), so the last
// incrementer (old==NBLK-1) knows all reads happened; tie rows never appear
// in g_rowlist, so finalize writes don't overlap tile writes.
// ---------------------------------------------------------------------------
__global__ __launch_bounds__(256) void moe_gemm_kernel(
    const float* __restrict__ x, const float* __restrict__ W,
    float* __restrict__ out)
{
    const int T = blockIdx.x;
    const int n0 = blockIdx.y * 64;

    __shared__ int   rlds[64];
    __shared__ float xs[16][68];         // [k][m], padded stride 68
    __shared__ float wst[16][64];        // [k][n]
    __shared__ int   s_last;

    const int t = threadIdx.x;

    int e = 0, base = 0, cnt = 0;
    for (; e < NE; ++e) {
        cnt = g_meta[e];
        const int te = (cnt + 63) >> 6;
        if (T < base + te) break;
        base += te;
    }

    if (e < NE) {                        // mapped to a real tile
        const int r0 = (T - base) * 64;

        if (t < 64) {
            const int idx = r0 + t;
            const int bb = g_rowlist[e * NB + min(idx, cnt - 1)];  // cnt>=1 here
            rlds[t] = (idx < cnt) ? bb : (bb | 0x40000000);        // bit30 = tail
        }
        __syncthreads();

        const int xm = t >> 2, xc = t & 3;
        const int wk = t >> 4, wc = t & 15;
        const float* xptr = x + (rlds[xm] & 0x3FFFFFFF) * NI + xc * 4;
        const float* wptr = W + e * NI * NO + wk * NO + n0 + wc * 4;
        float4 xr = *(const float4*)xptr;
        float4 wr = *(const float4*)wptr;

        const int tm = t >> 4, tn = t & 15;
        float acc[4][4] = {{0.f}};

        #pragma unroll 1
        for (int step = 0; step < 16; ++step) {
            __syncthreads();
            xs[xc * 4 + 0][xm] = xr.x;
            xs[xc * 4 + 1][xm] = xr.y;
            xs[xc * 4 + 2][xm] = xr.z;
            xs[xc * 4 + 3][xm] = xr.w;
            *(float4*)&wst[wk][wc * 4] = wr;
            __syncthreads();
            if (step < 15) {                          // prefetch next K-slab
                xr = *(const float4*)(xptr + (step + 1) * 16);
                wr = *(const float4*)(wptr + (step + 1) * 16 * NO);
            }
            #pragma unroll
            for (int k = 0; k < 16; ++k) {
                const float4 a  = *(const float4*)&xs[k][tm * 4];
                const float4 bv = *(const float4*)&wst[k][tn * 4];
                acc[0][0] += a.x * bv.x; acc[0][1] += a.x * bv.y; acc[0][2] += a.x * bv.z; acc[0][3] += a.x * bv.w;
                acc[1][0] += a.y * bv.x; acc[1][1] += a.y * bv.y; acc[1][2] += a.y * bv.z; acc[1][3] += a.y * bv.w;
                acc[2][0] += a.z * bv.x; acc[2][1] += a.z * bv.y; acc[2][2] += a.z * bv.z; acc[2][3] += a.z * bv.w;
                acc[3][0] += a.w * bv.x; acc[3][1] += a.w * bv.y; acc[3][2] += a.w * bv.z; acc[3][3] += a.w * bv.w;
            }
        }

        #pragma unroll
        for (int r = 0; r < 4; ++r) {
            const int info = rlds[tm * 4 + r];
            if (!(info & 0x40000000)) {
                float4 v;
                v.x = acc[r][0]; v.y = acc[r][1]; v.z = acc[r][2]; v.w = acc[r][3];
                *(float4*)&out[(info & 0x3FFFFFFF) * NO + n0 + tn * 4] = v;
            }
        }
    }

    // ---------------- completion protocol + last-block finalize ----------------
    __threadfence();                     // make out-writes device-visible
    __syncthreads();
    if (t == 0) s_last = (atomicAdd(&g_done, 1) == NBLK - 1) ? 1 : 0;
    __syncthreads();
    if (s_last) {
        float* xl = &xs[0][0];           // reuse LDS, 256 floats
        const int n = g_meta[8];
        for (int idx = 0; idx < n; ++idx) {
            const int packed = g_ovf[idx];
            const int b = packed & 0xFFFF;
            const int mask = packed >> 16;
            __syncthreads();
            xl[t] = x[b * NI + t];
            __syncthreads();
            float acc = 0.0f;
            for (int ee = 0; ee < NE; ++ee) {
                if (mask & (1 << ee)) {
                    const float* wp = W + ee * NI * NO + t;
                    for (int i = 0; i < NI; ++i) acc += xl[i] * wp[i * NO];
                }
            }
            out[b * NO + t] = acc;
        }
        __syncthreads();                 // all reads of g_meta/g_ovf done
        if (t < 16) g_meta[t] = 0;       // restore invariants for next call
        if (t == 16) g_done = 0;
    }
}

extern "C" void kernel_launch(void* const* d_in, const int* in_sizes, int n_in,
                              void* d_out, int out_size, void* d_ws, size_t ws_size,
                              hipStream_t stream)
{
    const float* x  = (const float*)d_in[0];
    const float* W  = (const float*)d_in[1];
    const float* Wp = (const float*)d_in[2];
    const float* bp = (const float*)d_in[3];
    float* out = (float*)d_out;

    router_kernel<<<NB / 4, 256, 0, stream>>>(x, Wp, bp);

    dim3 grid(72, 4);                    // 72*4 == NBLK
    moe_gemm_kernel<<<grid, 256, 0, stream>>>(x, W, out);
}

// Round 17
// 130.485 us; speedup vs baseline: 1.4216x; 1.0016x over previous
//
#include <hip/hip_runtime.h>
#include <hip/hip_bf16.h>

#define NB 4096   // batch rows
#define NI 256    // input dim
#define NO 256    // output dim
#define NE 8      // experts
#define NBLK 288  // gemm grid = 72 x 4

// Device-global scratch. Invariants at entry to every call:
//   g_meta == 0, g_done == 0  (zero-init at load; last gemm block resets both)
__device__ int g_meta[16];          // [0..7] per-expert count, [8] overflow count
__device__ int g_rowlist[NE * NB];  // per-expert row indices (single-hot rows)
__device__ int g_ovf[NB];           // packed (mask<<16)|row for tie rows
__device__ int g_done = 0;          // gemm blocks completed

// ---------------------------------------------------------------------------
// Router: g = sigmoid(x @ Wp^T + bp); bin rows by argmax expert (ties -> ovf).
// One wave per row; lane l owns x[b][4l..4l+3].
// ---------------------------------------------------------------------------
__global__ __launch_bounds__(256) void router_kernel(
    const float* __restrict__ x, const float* __restrict__ Wp,
    const float* __restrict__ bp)
{
    __shared__ float wplds[NE * NI];
    const int t = threadIdx.x;
    #pragma unroll
    for (int i = 0; i < NE * NI; i += 256 * 4)
        *(float4*)&wplds[i + t * 4] = *(const float4*)&Wp[i + t * 4];
    __syncthreads();

    const int lane = t & 63;
    const int b = blockIdx.x * 4 + (t >> 6);
    const float4 xv = *(const float4*)&x[b * NI + lane * 4];

    float p[NE];
    #pragma unroll
    for (int e = 0; e < NE; ++e) {
        const float4 wv = *(const float4*)&wplds[e * NI + lane * 4];
        p[e] = xv.x * wv.x + xv.y * wv.y + xv.z * wv.z + xv.w * wv.w;
    }
    #pragma unroll
    for (int off = 32; off >= 1; off >>= 1) {
        #pragma unroll
        for (int e = 0; e < NE; ++e) p[e] += __shfl_xor(p[e], off);
    }
    float g[NE], gmax = -1e30f;
    #pragma unroll
    for (int e = 0; e < NE; ++e) {
        g[e] = 1.0f / (1.0f + expf(-(p[e] + bp[e])));
        gmax = fmaxf(gmax, g[e]);
    }
    int mask = 0;
    #pragma unroll
    for (int e = 0; e < NE; ++e) mask |= (g[e] == gmax) ? (1 << e) : 0;

    if (lane == 0) {
        if (__popc(mask) == 1) {
            const int e = __ffs(mask) - 1;
            const int pos = atomicAdd(&g_meta[e], 1);
            g_rowlist[e * NB + pos] = b;
        } else {                       // tie: rare slow path
            const int pos = atomicAdd(&g_meta[8], 1);
            g_ovf[pos] = (mask << 16) | b;
        }
    }
}

// ---------------------------------------------------------------------------
// Grouped GEMM over binned rows + last-block finalize (tie rows, meta reset).
// __launch_bounds__(256, 1): round 16 showed the default allocation (40 VGPR)
// leaves no registers for ILP -> every ds_read_b128 serializes (46.5us,
// VALUBusy 7.7%). min-1-wave/EU frees the allocator to pipeline.
// ---------------------------------------------------------------------------
__global__ __launch_bounds__(256, 1) void moe_gemm_kernel(
    const float* __restrict__ x, const float* __restrict__ W,
    float* __restrict__ out)
{
    const int T = blockIdx.x;
    const int n0 = blockIdx.y * 64;

    __shared__ int   rlds[64];
    __shared__ float xs[16][68];         // [k][m], padded stride 68
    __shared__ float wst[16][64];        // [k][n]
    __shared__ int   s_last;

    const int t = threadIdx.x;

    int e = 0, base = 0, cnt = 0;
    for (; e < NE; ++e) {
        cnt = g_meta[e];
        const int te = (cnt + 63) >> 6;
        if (T < base + te) break;
        base += te;
    }

    if (e < NE) {                        // mapped to a real tile
        const int r0 = (T - base) * 64;

        if (t < 64) {
            const int idx = r0 + t;
            const int bb = g_rowlist[e * NB + min(idx, cnt - 1)];  // cnt>=1 here
            rlds[t] = (idx < cnt) ? bb : (bb | 0x40000000);        // bit30 = tail
        }
        __syncthreads();

        const int xm = t >> 2, xc = t & 3;
        const int wk = t >> 4, wc = t & 15;
        const float* xptr = x + (rlds[xm] & 0x3FFFFFFF) * NI + xc * 4;
        const float* wptr = W + e * NI * NO + wk * NO + n0 + wc * 4;
        float4 xr = *(const float4*)xptr;
        float4 wr = *(const float4*)wptr;

        const int tm = t >> 4, tn = t & 15;
        float acc[4][4] = {{0.f}};

        #pragma unroll 1
        for (int step = 0; step < 16; ++step) {
            __syncthreads();
            xs[xc * 4 + 0][xm] = xr.x;
            xs[xc * 4 + 1][xm] = xr.y;
            xs[xc * 4 + 2][xm] = xr.z;
            xs[xc * 4 + 3][xm] = xr.w;
            *(float4*)&wst[wk][wc * 4] = wr;
            __syncthreads();
            if (step < 15) {                          // prefetch next K-slab
                xr = *(const float4*)(xptr + (step + 1) * 16);
                wr = *(const float4*)(wptr + (step + 1) * 16 * NO);
            }
            #pragma unroll
            for (int k = 0; k < 16; ++k) {
                const float4 a  = *(const float4*)&xs[k][tm * 4];
                const float4 bv = *(const float4*)&wst[k][tn * 4];
                acc[0][0] += a.x * bv.x; acc[0][1] += a.x * bv.y; acc[0][2] += a.x * bv.z; acc[0][3] += a.x * bv.w;
                acc[1][0] += a.y * bv.x; acc[1][1] += a.y * bv.y; acc[1][2] += a.y * bv.z; acc[1][3] += a.y * bv.w;
                acc[2][0] += a.z * bv.x; acc[2][1] += a.z * bv.y; acc[2][2] += a.z * bv.z; acc[2][3] += a.z * bv.w;
                acc[3][0] += a.w * bv.x; acc[3][1] += a.w * bv.y; acc[3][2] += a.w * bv.z; acc[3][3] += a.w * bv.w;
            }
        }

        #pragma unroll
        for (int r = 0; r < 4; ++r) {
            const int info = rlds[tm * 4 + r];
            if (!(info & 0x40000000)) {
                float4 v;
                v.x = acc[r][0]; v.y = acc[r][1]; v.z = acc[r][2]; v.w = acc[r][3];
                *(float4*)&out[(info & 0x3FFFFFFF) * NO + n0 + tn * 4] = v;
            }
        }
    }

    // ---------------- completion protocol + last-block finalize ----------------
    __threadfence();                     // make out-writes device-visible
    __syncthreads();
    if (t == 0) s_last = (atomicAdd(&g_done, 1) == NBLK - 1) ? 1 : 0;
    __syncthreads();
    if (s_last) {
        float* xl = &xs[0][0];           // reuse LDS, 256 floats
        const int n = g_meta[8];
        for (int idx = 0; idx < n; ++idx) {
            const int packed = g_ovf[idx];
            const int b = packed & 0xFFFF;
            const int mask = packed >> 16;
            __syncthreads();
            xl[t] = x[b * NI + t];
            __syncthreads();
            float acc = 0.0f;
            for (int ee = 0; ee < NE; ++ee) {
                if (mask & (1 << ee)) {
                    const float* wp = W + ee * NI * NO + t;
                    for (int i = 0; i < NI; ++i) acc += xl[i] * wp[i * NO];
                }
            }
            out[b * NO + t] = acc;
        }
        __syncthreads();                 // all reads of g_meta/g_ovf done
        if (t < 16) g_meta[t] = 0;       // restore invariants for next call
        if (t == 16) g_done = 0;
    }
}

extern "C" void kernel_launch(void* const* d_in, const int* in_sizes, int n_in,
                              void* d_out, int out_size, void* d_ws, size_t ws_size,
                              hipStream_t stream)
{
    const float* x  = (const float*)d_in[0];
    const float* W  = (const float*)d_in[1];
    const float* Wp = (const float*)d_in[2];
    const float* bp = (const float*)d_in[3];
    float* out = (float*)d_out;

    router_kernel<<<NB / 4, 256, 0, stream>>>(x, Wp, bp);

    dim3 grid(72, 4);                    // 72*4 == NBLK
    moe_gemm_kernel<<<grid, 256, 0, stream>>>(x, W, out);
}